// Round 22
// baseline (75.188 us; speedup 1.0000x reference)
//
#include <hip/hip_runtime.h>

#define LN_EPS 1e-5f

typedef __fp16 h2 __attribute__((ext_vector_type(2)));

static constexpr int Hc  = 512;
static constexpr int Fc  = 16;
static constexpr int Sc  = 1024;
static constexpr int NW  = 4096;     // total waves; row stride for grid-stride

// ---- prologue: bsum[h] = sum_i b[i][h] (512 floats into d_ws) ----
__global__ void bsum_kernel(const float* __restrict__ b, float* __restrict__ bsum) {
    int h = blockIdx.x * 64 + threadIdx.x;
    float s = 0.f;
#pragma unroll
    for (int i = 0; i < Fc; ++i) s += b[i * Hc + h];
    bsum[h] = s;
}

// ---- DPP wave64 sum: 6 VALU steps + readlane, no LDS, no barriers ----
template <int CTRL, int RMASK>
__device__ __forceinline__ float dpp_add(float v) {
    int t = __builtin_amdgcn_update_dpp(0, __float_as_int(v), CTRL, RMASK, 0xf, true);
    return v + __int_as_float(t);
}
__device__ __forceinline__ float wave_sum64(float v) {
    v = dpp_add<0x111, 0xf>(v);
    v = dpp_add<0x112, 0xf>(v);
    v = dpp_add<0x114, 0xf>(v);
    v = dpp_add<0x118, 0xf>(v);
    v = dpp_add<0x142, 0xa>(v);
    v = dpp_add<0x143, 0xc>(v);
    return __int_as_float(__builtin_amdgcn_readlane(__float_as_int(v), 63));
}
__device__ __forceinline__ float rdlane(float v, int l) {
    return __int_as_float(__builtin_amdgcn_readlane(__float_as_int(v), l));
}

// bf16 pack (W panel, R12-validated): lo = 1 shift, hi = free.
__device__ __forceinline__ unsigned rne16(float f) {
    unsigned u = __float_as_uint(f);
    return (u + 0x7fffu + ((u >> 16) & 1u)) >> 16;
}
__device__ __forceinline__ unsigned pack2(float lo, float hi) {
    return rne16(lo) | (rne16(hi) << 16);
}
__device__ __forceinline__ float lo_f(unsigned p) { return __uint_as_float(p << 16); }
__device__ __forceinline__ float hi_f(unsigned p) { return __uint_as_float(p); }

// f16 pack/unpack (result + invariant compression; |v|<=6 -> err <= 0.003)
__device__ __forceinline__ unsigned pk16(float lo, float hi) {
    return __builtin_bit_cast(unsigned, __builtin_amdgcn_cvt_pkrtz(lo, hi));
}
__device__ __forceinline__ float u16lo(unsigned p) {
    h2 v = __builtin_bit_cast(h2, p); return (float)v.x;
}
__device__ __forceinline__ float u16hi(unsigned p) {
    h2 v = __builtin_bit_cast(h2, p); return (float)v.y;
}

// ---- fused: wave w, rows r = w + k*NW; dense band + DOUBLE-BUFFERED bursts
// AT 4 WAVES/SIMD. R21 proved decoupling (+8-10% at fixed occupancy, won at
// 2w); R12/R18 proved the 4-waves tier (+8-13%). Never combined: to fit both
// result buffers in the 128-reg cap, burst buffers and invariants are packed
// f16 (cvt_pkrtz): W 64 + xq 8 + resA/B 32 + inv 12 + misc ~10 = ~126.
// LB(256,2) caps at 128 -> 4 waves/SIMD. Spill tripwire: FETCH/WRITE inflate.
__global__ __launch_bounds__(256, 2) void fused_kernel(
    const float* __restrict__ x, const float* __restrict__ W,
    const float* __restrict__ emb, const float* __restrict__ bsum,
    const float* __restrict__ gamma, const float* __restrict__ beta,
    float* __restrict__ out)
{
    const int lane = threadIdx.x & 63;
    const int w    = (blockIdx.x << 2) | (threadIdx.x >> 6);   // 0..4095
    const int s    = w & (Sc - 1);
    const int h0 = lane * 4, h1 = h0 + 256;

    // packed W panel: 16 K-rows x 8 cols per lane in 64 u32 (bf16)
    unsigned p00[Fc], p01[Fc], p10[Fc], p11[Fc];
#pragma unroll
    for (int i = 0; i < Fc; ++i) {
        const float4 wa = *reinterpret_cast<const float4*>(&W[i * Hc + h0]);
        const float4 wb = *reinterpret_cast<const float4*>(&W[i * Hc + h1]);
        p00[i] = pack2(wa.x, wa.y);
        p01[i] = pack2(wa.z, wa.w);
        p10[i] = pack2(wb.x, wb.y);
        p11[i] = pack2(wb.z, wb.w);
    }

    // x for all 32 rows up front
    const int sub = lane >> 4, i16 = lane & 15;
    float xq[8];
#pragma unroll
    for (int q = 0; q < 8; ++q)
        xq[q] = __builtin_nontemporal_load(
            &x[((size_t)(q * 4 + sub) * NW + w) * Fc + i16]);

    // invariants packed f16: ebs = emb[s]+bsum; gamma; beta (12 u32)
    unsigned e01, e23, e45, e67, gp01, gp23, gp45, gp67, bp01, bp23, bp45, bp67;
    {
        const float4 e0  = *reinterpret_cast<const float4*>(&emb[(size_t)s * Hc + h0]);
        const float4 e1  = *reinterpret_cast<const float4*>(&emb[(size_t)s * Hc + h1]);
        const float4 bs0 = *reinterpret_cast<const float4*>(&bsum[h0]);
        const float4 bs1 = *reinterpret_cast<const float4*>(&bsum[h1]);
        e01 = pk16(e0.x + bs0.x, e0.y + bs0.y);
        e23 = pk16(e0.z + bs0.z, e0.w + bs0.w);
        e45 = pk16(e1.x + bs1.x, e1.y + bs1.y);
        e67 = pk16(e1.z + bs1.z, e1.w + bs1.w);
        const float4 g0  = *reinterpret_cast<const float4*>(&gamma[h0]);
        const float4 g1  = *reinterpret_cast<const float4*>(&gamma[h1]);
        const float4 be0 = *reinterpret_cast<const float4*>(&beta[h0]);
        const float4 be1 = *reinterpret_cast<const float4*>(&beta[h1]);
        gp01 = pk16(g0.x, g0.y); gp23 = pk16(g0.z, g0.w);
        gp45 = pk16(g1.x, g1.y); gp67 = pk16(g1.z, g1.w);
        bp01 = pk16(be0.x, be0.y); bp23 = pk16(be0.z, be0.w);
        bp45 = pk16(be1.x, be1.y); bp67 = pk16(be1.z, be1.w);
    }

    unsigned rA[16], rB[16];   // f16-packed burst buffers (static idx via unroll)

    // one 4-row batch: compute 4 rows into packed res, then burst-store 8
    auto BATCH = [&](int q, const float xsrc, unsigned* res) {
        // ---- compute phase ----
#pragma unroll
        for (int u = 0; u < 4; ++u) {
            float a0x = u16lo(e01), a0y = u16hi(e01);
            float a0z = u16lo(e23), a0w = u16hi(e23);
            float a1x = u16lo(e45), a1y = u16hi(e45);
            float a1z = u16lo(e67), a1w = u16hi(e67);
#pragma unroll
            for (int i = 0; i < Fc; ++i) {
                const float xi = rdlane(xsrc, u * 16 + i);   // compile-time lane
                a0x = fmaf(xi, lo_f(p00[i]), a0x);
                a0y = fmaf(xi, hi_f(p00[i]), a0y);
                a0z = fmaf(xi, lo_f(p01[i]), a0z);
                a0w = fmaf(xi, hi_f(p01[i]), a0w);
                a1x = fmaf(xi, lo_f(p10[i]), a1x);
                a1y = fmaf(xi, hi_f(p10[i]), a1y);
                a1z = fmaf(xi, lo_f(p11[i]), a1z);
                a1w = fmaf(xi, hi_f(p11[i]), a1w);
            }

            float psum = a0x + a0y + a0z + a0w + a1x + a1y + a1z + a1w;
            float pssq = fmaf(a0x, a0x, fmaf(a0y, a0y, fmaf(a0z, a0z, a0w * a0w)));
            pssq = fmaf(a1x, a1x, fmaf(a1y, a1y, fmaf(a1z, a1z, fmaf(a1w, a1w, pssq))));

            const float sum = wave_sum64(psum);
            const float ssq = wave_sum64(pssq);

            const float mean = sum * (1.0f / 512.0f);
            const float var  = ssq * (1.0f / 512.0f) - mean * mean;
            const float rs   = rsqrtf(var + LN_EPS);
            const float nmrs = -mean * rs;

            res[u * 4 + 0] = pk16(
                fmaf(fmaf(a0x, rs, nmrs), u16lo(gp01), u16lo(bp01)),
                fmaf(fmaf(a0y, rs, nmrs), u16hi(gp01), u16hi(bp01)));
            res[u * 4 + 1] = pk16(
                fmaf(fmaf(a0z, rs, nmrs), u16lo(gp23), u16lo(bp23)),
                fmaf(fmaf(a0w, rs, nmrs), u16hi(gp23), u16hi(bp23)));
            res[u * 4 + 2] = pk16(
                fmaf(fmaf(a1x, rs, nmrs), u16lo(gp45), u16lo(bp45)),
                fmaf(fmaf(a1y, rs, nmrs), u16hi(gp45), u16hi(bp45)));
            res[u * 4 + 3] = pk16(
                fmaf(fmaf(a1z, rs, nmrs), u16lo(gp67), u16lo(bp67)),
                fmaf(fmaf(a1w, rs, nmrs), u16hi(gp67), u16hi(bp67)));
        }

        // ---- burst phase: unpack + 8 stores back-to-back ----
#pragma unroll
        for (int u = 0; u < 4; ++u) {
            float4 r0, r1;
            r0.x = u16lo(res[u * 4 + 0]); r0.y = u16hi(res[u * 4 + 0]);
            r0.z = u16lo(res[u * 4 + 1]); r0.w = u16hi(res[u * 4 + 1]);
            r1.x = u16lo(res[u * 4 + 2]); r1.y = u16hi(res[u * 4 + 2]);
            r1.z = u16lo(res[u * 4 + 3]); r1.w = u16hi(res[u * 4 + 3]);
            float* orow = out + ((size_t)(q * 4 + u) * NW + w) * Hc;
            *reinterpret_cast<float4*>(&orow[h0]) = r0;
            *reinterpret_cast<float4*>(&orow[h1]) = r1;
        }
    };

#pragma unroll 1
    for (int qq = 0; qq < 4; ++qq) {
        BATCH(2 * qq,     xq[0], rA);   // buffer A
        BATCH(2 * qq + 1, xq[1], rB);   // buffer B (A's stores stay in flight)
#pragma unroll
        for (int j = 0; j < 6; ++j) xq[j] = xq[j + 2];
    }
}

extern "C" void kernel_launch(void* const* d_in, const int* in_sizes, int n_in,
                              void* d_out, int out_size, void* d_ws, size_t ws_size,
                              hipStream_t stream) {
    const float* x     = (const float*)d_in[0];
    const float* W     = (const float*)d_in[1];
    const float* b     = (const float*)d_in[2];
    const float* emb   = (const float*)d_in[3];
    const float* gamma = (const float*)d_in[4];
    const float* beta  = (const float*)d_in[5];
    float* out  = (float*)d_out;
    float* bsum = (float*)d_ws;     // 512 floats

    bsum_kernel<<<Hc / 64, 64, 0, stream>>>(b, bsum);

    const int blocks = NW / 4;   // 1024 blocks x 4 waves
    fused_kernel<<<blocks, 256, 0, stream>>>(x, W, emb, bsum, gamma, beta, out);
}